// Round 1
// baseline (16023.755 us; speedup 1.0000x reference)
//
#include <hip/hip_runtime.h>
#include <math.h>

#define N_EMBD   1024
#define N_HEADS  16
#define HEAD_DIM 64
#define TBLK     1024
#define NLAYER   6
#define VOCAB    32000
#define BATCH    2
#define ROWS     (BATCH * TBLK)      // 2048
#define EPS      1e-5f
#define SCALE    0.03125f            // N_EMBD^-0.5 (reference scales by full n_embd)

// ---------------------------------------------------------------------------
// Embedding gather: x[row,:] = emb[idx[row],:]
// ---------------------------------------------------------------------------
__global__ __launch_bounds__(256) void embed_kernel(const int* __restrict__ idx,
                                                    const float* __restrict__ emb,
                                                    float* __restrict__ x) {
    int row = blockIdx.x;
    int tok = idx[row];
    const float4* src = (const float4*)(emb + (size_t)tok * N_EMBD);
    float4* dst = (float4*)(x + (size_t)row * N_EMBD);
    dst[threadIdx.x] = src[threadIdx.x];   // 256 threads * 4 floats = 1024
}

// ---------------------------------------------------------------------------
// LayerNorm: one block (256 thr) per row of 1024
// ---------------------------------------------------------------------------
__global__ __launch_bounds__(256) void ln_kernel(const float* __restrict__ x,
                                                 const float* __restrict__ g,
                                                 const float* __restrict__ b,
                                                 float* __restrict__ y) {
    int row = blockIdx.x;
    int tid = threadIdx.x;
    const float4* xr = (const float4*)(x + (size_t)row * N_EMBD);
    float4 v = xr[tid];
    __shared__ float red[4];

    float s = v.x + v.y + v.z + v.w;
    #pragma unroll
    for (int off = 32; off; off >>= 1) s += __shfl_down(s, off);
    if ((tid & 63) == 0) red[tid >> 6] = s;
    __syncthreads();
    float mean = (red[0] + red[1] + red[2] + red[3]) * (1.0f / N_EMBD);

    float dx = v.x - mean, dy = v.y - mean, dz = v.z - mean, dw = v.w - mean;
    float sq = dx * dx + dy * dy + dz * dz + dw * dw;
    __syncthreads();
    #pragma unroll
    for (int off = 32; off; off >>= 1) sq += __shfl_down(sq, off);
    if ((tid & 63) == 0) red[tid >> 6] = sq;
    __syncthreads();
    float var = (red[0] + red[1] + red[2] + red[3]) * (1.0f / N_EMBD);
    float inv = rsqrtf(var + EPS);

    float4 gv = ((const float4*)g)[tid];
    float4 bv = ((const float4*)b)[tid];
    float4 o;
    o.x = dx * inv * gv.x + bv.x;
    o.y = dy * inv * gv.y + bv.y;
    o.z = dz * inv * gv.z + bv.z;
    o.w = dw * inv * gv.w + bv.w;
    ((float4*)(y + (size_t)row * N_EMBD))[tid] = o;
}

// ---------------------------------------------------------------------------
// QKV GEMM with fused RoPE. Grid: (m-tile 0..31, head 0..15, sel 0..2).
// A = y [2048 x 1024], B = w{q,k,v}[h] [1024 x 64], C scattered to [B,H,T,D].
// 64x64x16 tile, 256 threads, 4x4 accum per thread.
// ---------------------------------------------------------------------------
__global__ __launch_bounds__(256) void qkv_gemm_kernel(
    const float* __restrict__ y, const float* __restrict__ wq,
    const float* __restrict__ wk, const float* __restrict__ wv,
    float* __restrict__ q, float* __restrict__ k, float* __restrict__ v) {
    const int mt  = blockIdx.x;
    const int h   = blockIdx.y;
    const int sel = blockIdx.z;
    const float* W = (sel == 0 ? wq : sel == 1 ? wk : wv) + (size_t)h * (N_EMBD * HEAD_DIM);
    float* C = (sel == 0 ? q : sel == 1 ? k : v);

    __shared__ float As[16][65];
    __shared__ float Bs[16][64];
    const int tid = threadIdx.x;
    const int tx = tid & 15, ty = tid >> 4;
    const int amr = tid >> 2, akq = tid & 3;
    const int bkr = tid >> 4, bnq = tid & 15;
    const int m0 = mt * 64;

    float acc[4][4] = {};
    for (int k0 = 0; k0 < N_EMBD; k0 += 16) {
        float4 av = *(const float4*)(y + (size_t)(m0 + amr) * N_EMBD + k0 + akq * 4);
        float4 bv = *(const float4*)(W + (size_t)(k0 + bkr) * HEAD_DIM + bnq * 4);
        __syncthreads();
        As[akq * 4 + 0][amr] = av.x;
        As[akq * 4 + 1][amr] = av.y;
        As[akq * 4 + 2][amr] = av.z;
        As[akq * 4 + 3][amr] = av.w;
        *(float4*)&Bs[bkr][bnq * 4] = bv;
        __syncthreads();
        #pragma unroll
        for (int kk = 0; kk < 16; ++kk) {
            float a[4], bb[4];
            #pragma unroll
            for (int i = 0; i < 4; ++i) a[i] = As[kk][ty * 4 + i];
            #pragma unroll
            for (int j = 0; j < 4; ++j) bb[j] = Bs[kk][tx * 4 + j];
            #pragma unroll
            for (int i = 0; i < 4; ++i)
                #pragma unroll
                for (int j = 0; j < 4; ++j) acc[i][j] += a[i] * bb[j];
        }
    }

    const int b  = m0 >> 10;
    const int d0 = tx * 4;
    // rope frequencies for the two pairs (d0,d0+1) and (d0+2,d0+3)
    const float inv0 = powf(10000.0f, -(float)d0 / 64.0f);
    const float inv1 = powf(10000.0f, -(float)(d0 + 2) / 64.0f);
    #pragma unroll
    for (int i = 0; i < 4; ++i) {
        int m = m0 + ty * 4 + i;
        int t = m & (TBLK - 1);
        float r0 = acc[i][0], r1 = acc[i][1], r2 = acc[i][2], r3 = acc[i][3];
        if (sel < 2) {
            float s0, c0, s1, c1;
            sincosf((float)t * inv0, &s0, &c0);
            sincosf((float)t * inv1, &s1, &c1);
            float o0 = r0 * c0 - r1 * s0;
            float o1 = r0 * s0 + r1 * c0;
            float o2 = r2 * c1 - r3 * s1;
            float o3 = r2 * s1 + r3 * c1;
            r0 = o0; r1 = o1; r2 = o2; r3 = o3;
        }
        float4 res; res.x = r0; res.y = r1; res.z = r2; res.w = r3;
        *(float4*)(C + (((size_t)(b * N_HEADS + h) * TBLK + t) * HEAD_DIM + d0)) = res;
    }
}

// ---------------------------------------------------------------------------
// Attention: one 64-thread block per (t, h, b). Online softmax over s-tiles.
// ---------------------------------------------------------------------------
__global__ __launch_bounds__(64) void attn_kernel(const float* __restrict__ q,
                                                  const float* __restrict__ k,
                                                  const float* __restrict__ v,
                                                  float* __restrict__ o) {
    const int t = blockIdx.x, h = blockIdx.y, b = blockIdx.z;
    const int lane = threadIdx.x;
    __shared__ float kt[64][65];   // padded: score loop reads kt[lane][d]
    __shared__ float vt[64][64];   // unpadded: o loop reads vt[j][lane] (2-way, free)
    __shared__ float qs[64];
    __shared__ float ps[64];

    const size_t bh = (size_t)(b * N_HEADS + h) * TBLK * HEAD_DIM;
    qs[lane] = q[bh + (size_t)t * HEAD_DIM + lane];

    float m = -INFINITY, l = 0.0f, acc = 0.0f;
    const float* kb = k + bh;
    const float* vb = v + bh;

    for (int s0 = 0; s0 <= t; s0 += 64) {
        __syncthreads();   // protect kt/vt (and qs on first iter) readers/writers
        #pragma unroll
        for (int c = 0; c < 16; ++c) {
            float4 kv = *(const float4*)(kb + (size_t)(s0 + lane) * HEAD_DIM + c * 4);
            kt[lane][c * 4 + 0] = kv.x; kt[lane][c * 4 + 1] = kv.y;
            kt[lane][c * 4 + 2] = kv.z; kt[lane][c * 4 + 3] = kv.w;
            float4 vv = *(const float4*)(vb + (size_t)(s0 + lane) * HEAD_DIM + c * 4);
            vt[lane][c * 4 + 0] = vv.x; vt[lane][c * 4 + 1] = vv.y;
            vt[lane][c * 4 + 2] = vv.z; vt[lane][c * 4 + 3] = vv.w;
        }
        __syncthreads();

        // scores: thread `lane` handles s = s0+lane
        float sc = 0.0f;
        #pragma unroll
        for (int d = 0; d < 64; ++d) sc += qs[d] * kt[lane][d];
        sc *= SCALE;
        if (s0 + lane > t) sc = -INFINITY;

        float mx = sc;
        #pragma unroll
        for (int off = 32; off; off >>= 1) mx = fmaxf(mx, __shfl_xor(mx, off));
        float mnew = fmaxf(m, mx);
        float p = expf(sc - mnew);          // exp(-inf)=0 for masked
        float rowsum = p;
        #pragma unroll
        for (int off = 32; off; off >>= 1) rowsum += __shfl_xor(rowsum, off);
        ps[lane] = p;
        __syncthreads();

        float alpha = expf(m - mnew);        // first iter: exp(-inf)=0, acc=0 anyway
        l = l * alpha + rowsum;
        m = mnew;
        acc *= alpha;
        #pragma unroll
        for (int j = 0; j < 64; ++j) acc += ps[j] * vt[j][lane];
    }
    o[bh + (size_t)t * HEAD_DIM + lane] = acc / l;
}

// ---------------------------------------------------------------------------
// Generic fp32 GEMM: C[M,N] = (RESIDUAL? C : 0) + A[M,K]*B[K,N] + bias, opt ReLU.
// GATHER_A: A is o in [B,H,T,D] layout, logical row m=b*T+t, col k=h*64+d.
// 64x64x16 tiles, 256 threads, 4x4 per thread.
// ---------------------------------------------------------------------------
template <bool GATHER_A, bool RESIDUAL, bool RELU>
__global__ __launch_bounds__(256) void gemm_kernel(
    const float* __restrict__ A, const float* __restrict__ B,
    const float* __restrict__ bias, float* __restrict__ C,
    int M, int N, int K) {
    __shared__ float As[16][65];
    __shared__ float Bs[16][64];
    const int tid = threadIdx.x;
    const int tx = tid & 15, ty = tid >> 4;
    const int amr = tid >> 2, akq = tid & 3;
    const int bkr = tid >> 4, bnq = tid & 15;
    const int m0 = blockIdx.y * 64, n0 = blockIdx.x * 64;

    float acc[4][4] = {};
    for (int k0 = 0; k0 < K; k0 += 16) {
        float4 av;
        if (GATHER_A) {
            int m = m0 + amr;
            int kk = k0 + akq * 4;
            int bb_ = m >> 10, t = m & (TBLK - 1), hh = kk >> 6, d = kk & 63;
            av = *(const float4*)(A + (((size_t)(bb_ * N_HEADS + hh) * TBLK + t) * HEAD_DIM + d));
        } else {
            av = *(const float4*)(A + (size_t)(m0 + amr) * K + k0 + akq * 4);
        }
        float4 bv = *(const float4*)(B + (size_t)(k0 + bkr) * N + n0 + bnq * 4);
        __syncthreads();
        As[akq * 4 + 0][amr] = av.x;
        As[akq * 4 + 1][amr] = av.y;
        As[akq * 4 + 2][amr] = av.z;
        As[akq * 4 + 3][amr] = av.w;
        *(float4*)&Bs[bkr][bnq * 4] = bv;
        __syncthreads();
        #pragma unroll
        for (int kk = 0; kk < 16; ++kk) {
            float a[4], bb[4];
            #pragma unroll
            for (int i = 0; i < 4; ++i) a[i] = As[kk][ty * 4 + i];
            #pragma unroll
            for (int j = 0; j < 4; ++j) bb[j] = Bs[kk][tx * 4 + j];
            #pragma unroll
            for (int i = 0; i < 4; ++i)
                #pragma unroll
                for (int j = 0; j < 4; ++j) acc[i][j] += a[i] * bb[j];
        }
    }

    float4 bz = *(const float4*)(bias + n0 + tx * 4);
    #pragma unroll
    for (int i = 0; i < 4; ++i) {
        int m = m0 + ty * 4 + i;
        float4* crow = (float4*)(C + (size_t)m * N + n0 + tx * 4);
        float4 res;
        if (RESIDUAL) res = *crow; else { res.x = res.y = res.z = res.w = 0.0f; }
        float r0 = acc[i][0] + bz.x + res.x;
        float r1 = acc[i][1] + bz.y + res.y;
        float r2 = acc[i][2] + bz.z + res.z;
        float r3 = acc[i][3] + bz.w + res.w;
        if (RELU) {
            r0 = fmaxf(r0, 0.0f); r1 = fmaxf(r1, 0.0f);
            r2 = fmaxf(r2, 0.0f); r3 = fmaxf(r3, 0.0f);
        }
        float4 wv; wv.x = r0; wv.y = r1; wv.z = r2; wv.w = r3;
        *crow = wv;
    }
}

// ---------------------------------------------------------------------------
// Per-row NLL from logits (log-softmax + gather target)
// ---------------------------------------------------------------------------
__global__ __launch_bounds__(256) void nll_kernel(const float* __restrict__ logits,
                                                  const int* __restrict__ targets,
                                                  float* __restrict__ nll) {
    int row = blockIdx.x;
    int tid = threadIdx.x;
    const float* lr = logits + (size_t)row * VOCAB;
    __shared__ float red[4];

    float mx = -INFINITY;
    for (int c = tid; c < VOCAB; c += 256) mx = fmaxf(mx, lr[c]);
    #pragma unroll
    for (int off = 32; off; off >>= 1) mx = fmaxf(mx, __shfl_xor(mx, off));
    if ((tid & 63) == 0) red[tid >> 6] = mx;
    __syncthreads();
    mx = fmaxf(fmaxf(red[0], red[1]), fmaxf(red[2], red[3]));

    float se = 0.0f;
    for (int c = tid; c < VOCAB; c += 256) se += expf(lr[c] - mx);
    #pragma unroll
    for (int off = 32; off; off >>= 1) se += __shfl_xor(se, off);
    __syncthreads();
    if ((tid & 63) == 0) red[tid >> 6] = se;
    __syncthreads();
    se = red[0] + red[1] + red[2] + red[3];

    if (tid == 0) {
        float lt = lr[targets[row]];
        nll[row] = -(lt - mx - logf(se));
    }
}

__global__ __launch_bounds__(256) void loss_reduce_kernel(const float* __restrict__ nll,
                                                          float* __restrict__ out) {
    int tid = threadIdx.x;
    float s = 0.0f;
    for (int i = tid; i < ROWS; i += 256) s += nll[i];
    #pragma unroll
    for (int off = 32; off; off >>= 1) s += __shfl_xor(s, off);
    __shared__ float red[4];
    if ((tid & 63) == 0) red[tid >> 6] = s;
    __syncthreads();
    if (tid == 0) out[0] = (red[0] + red[1] + red[2] + red[3]) * (1.0f / ROWS);
}

// ---------------------------------------------------------------------------
extern "C" void kernel_launch(void* const* d_in, const int* in_sizes, int n_in,
                              void* d_out, int out_size, void* d_ws, size_t ws_size,
                              hipStream_t stream) {
    const int*   idx     = (const int*)d_in[0];
    const int*   targets = (const int*)d_in[1];
    const float* emb     = (const float*)d_in[2];
    const float* wq      = (const float*)d_in[3];
    const float* wk      = (const float*)d_in[4];
    const float* wv      = (const float*)d_in[5];
    const float* wproj   = (const float*)d_in[6];
    const float* bproj   = (const float*)d_in[7];
    const float* w1      = (const float*)d_in[8];
    const float* b1      = (const float*)d_in[9];
    const float* w2      = (const float*)d_in[10];
    const float* b2      = (const float*)d_in[11];
    const float* ln1g    = (const float*)d_in[12];
    const float* ln1b    = (const float*)d_in[13];
    const float* ln2g    = (const float*)d_in[14];
    const float* ln2b    = (const float*)d_in[15];
    const float* lmw     = (const float*)d_in[16];
    const float* lmb     = (const float*)d_in[17];

    float* out = (float*)d_out;
    // x must survive until the LM-head GEMM → lives in d_ws (8.4 MB needed).
    float* x   = (float*)d_ws;
    float* nll = x + (size_t)ROWS * N_EMBD;
    // All other intermediates are dead before logits are written → use the
    // head of d_out (65.5M floats) as scratch; LM head overwrites it last.
    const size_t SEG = (size_t)ROWS * N_EMBD;      // 2,097,152 floats
    float* y   = out;
    float* q   = out + SEG;
    float* kk  = out + 2 * SEG;
    float* vv  = out + 3 * SEG;
    float* o   = out + 4 * SEG;
    float* act = out + 5 * SEG;                    // 8,388,608 floats, ends < 19M

    embed_kernel<<<ROWS, 256, 0, stream>>>(idx, emb, x);

    for (int l = 0; l < NLAYER; ++l) {
        const size_t wqkv_off  = (size_t)l * N_HEADS * N_EMBD * HEAD_DIM; // 1,048,576
        const size_t wproj_off = (size_t)l * N_EMBD * N_EMBD;             // 1,048,576
        const size_t w1_off    = (size_t)l * N_EMBD * 4 * N_EMBD;         // 4,194,304

        ln_kernel<<<ROWS, 256, 0, stream>>>(x, ln1g + l * N_EMBD, ln1b + l * N_EMBD, y);
        qkv_gemm_kernel<<<dim3(ROWS / 64, N_HEADS, 3), 256, 0, stream>>>(
            y, wq + wqkv_off, wk + wqkv_off, wv + wqkv_off, q, kk, vv);
        attn_kernel<<<dim3(TBLK, N_HEADS, BATCH), 64, 0, stream>>>(q, kk, vv, o);
        gemm_kernel<true, true, false><<<dim3(N_EMBD / 64, ROWS / 64), 256, 0, stream>>>(
            o, wproj + wproj_off, bproj + l * N_EMBD, x, ROWS, N_EMBD, N_EMBD);
        ln_kernel<<<ROWS, 256, 0, stream>>>(x, ln2g + l * N_EMBD, ln2b + l * N_EMBD, y);
        gemm_kernel<false, false, true><<<dim3(4 * N_EMBD / 64, ROWS / 64), 256, 0, stream>>>(
            y, w1 + w1_off, b1 + (size_t)l * 4 * N_EMBD, act, ROWS, 4 * N_EMBD, N_EMBD);
        gemm_kernel<false, true, false><<<dim3(N_EMBD / 64, ROWS / 64), 256, 0, stream>>>(
            act, w2 + w1_off, b2 + l * N_EMBD, x, ROWS, N_EMBD, 4 * N_EMBD);
    }

    gemm_kernel<false, false, false><<<dim3(VOCAB / 64, ROWS / 64), 256, 0, stream>>>(
        x, lmw, lmb, out, ROWS, VOCAB, N_EMBD);
    nll_kernel<<<ROWS, 256, 0, stream>>>(out, targets, nll);
    loss_reduce_kernel<<<1, 256, 0, stream>>>(nll, out + (size_t)ROWS * VOCAB);
}

// Round 2
// 3104.730 us; speedup vs baseline: 5.1611x; 5.1611x over previous
//
#include <hip/hip_runtime.h>
#include <math.h>

#define N_EMBD   1024
#define N_HEADS  16
#define HEAD_DIM 64
#define TBLK     1024
#define NLAYER   6
#define VOCAB    32000
#define BATCH    2
#define ROWS     (BATCH * TBLK)      // 2048
#define EPS      1e-5f
#define SCALE    0.03125f            // N_EMBD^-0.5 (reference scales by full n_embd)

typedef unsigned short u16;
typedef __bf16 bf16x8 __attribute__((ext_vector_type(8)));
typedef float  f32x4  __attribute__((ext_vector_type(4)));

__device__ __forceinline__ u16 f2bf(float f) {   // RNE float->bf16 bits
    unsigned x = __float_as_uint(f);
    return (u16)((x + 0x7fffu + ((x >> 16) & 1u)) >> 16);
}

__device__ __forceinline__ void glds16(const u16* g, u16* l) {
    __builtin_amdgcn_global_load_lds(
        (const __attribute__((address_space(1))) void*)g,
        (__attribute__((address_space(3))) void*)l, 16, 0, 0);
}

// ---------------------------------------------------------------------------
// Embedding gather (fp32 residual stream)
// ---------------------------------------------------------------------------
__global__ __launch_bounds__(256) void embed_kernel(const int* __restrict__ idx,
                                                    const float* __restrict__ emb,
                                                    float* __restrict__ x) {
    int row = blockIdx.x;
    int tok = idx[row];
    ((float4*)(x + (size_t)row * N_EMBD))[threadIdx.x] =
        ((const float4*)(emb + (size_t)tok * N_EMBD))[threadIdx.x];
}

// ---------------------------------------------------------------------------
// RoPE cos/sin tables: [1024][32] each
// ---------------------------------------------------------------------------
__global__ __launch_bounds__(256) void rope_table_kernel(float* __restrict__ cosT,
                                                         float* __restrict__ sinT) {
    int id = blockIdx.x * 256 + threadIdx.x;   // 32768 total
    int t = id >> 5, i = id & 31;
    float inv = powf(10000.0f, -(float)(2 * i) * (1.0f / 64.0f));
    float a = (float)t * inv;
    cosT[id] = cosf(a);
    sinT[id] = sinf(a);
}

// ---------------------------------------------------------------------------
// Transpose-convert fp32 [K][N] -> bf16 [N][K]; grid (N/32, K/32, slices)
// ---------------------------------------------------------------------------
__global__ __launch_bounds__(256) void convT_kernel(const float* __restrict__ src,
                                                    u16* __restrict__ dst,
                                                    int K, int N, long sS, long dS) {
    src += (size_t)blockIdx.z * sS;
    dst += (size_t)blockIdx.z * dS;
    const int n0 = blockIdx.x * 32, k0 = blockIdx.y * 32;
    __shared__ float tile[32][33];
    const int r = threadIdx.x >> 3, c4 = (threadIdx.x & 7) * 4;
    float4 v = *(const float4*)(src + (size_t)(k0 + r) * N + n0 + c4);
    tile[r][c4 + 0] = v.x; tile[r][c4 + 1] = v.y;
    tile[r][c4 + 2] = v.z; tile[r][c4 + 3] = v.w;
    __syncthreads();
    ushort4 o;
    o.x = f2bf(tile[c4 + 0][r]);
    o.y = f2bf(tile[c4 + 1][r]);
    o.z = f2bf(tile[c4 + 2][r]);
    o.w = f2bf(tile[c4 + 3][r]);
    *(ushort4*)(dst + (size_t)(n0 + r) * K + k0 + c4) = o;
}

// ---------------------------------------------------------------------------
// LayerNorm fp32 -> bf16
// ---------------------------------------------------------------------------
__global__ __launch_bounds__(256) void ln_kernel(const float* __restrict__ x,
                                                 const float* __restrict__ g,
                                                 const float* __restrict__ b,
                                                 u16* __restrict__ y) {
    int row = blockIdx.x;
    int tid = threadIdx.x;
    float4 v = ((const float4*)(x + (size_t)row * N_EMBD))[tid];
    __shared__ float red[4];

    float s = v.x + v.y + v.z + v.w;
    #pragma unroll
    for (int off = 32; off; off >>= 1) s += __shfl_down(s, off);
    if ((tid & 63) == 0) red[tid >> 6] = s;
    __syncthreads();
    float mean = (red[0] + red[1] + red[2] + red[3]) * (1.0f / N_EMBD);

    float dx = v.x - mean, dy = v.y - mean, dz = v.z - mean, dw = v.w - mean;
    float sq = dx * dx + dy * dy + dz * dz + dw * dw;
    __syncthreads();
    #pragma unroll
    for (int off = 32; off; off >>= 1) sq += __shfl_down(sq, off);
    if ((tid & 63) == 0) red[tid >> 6] = sq;
    __syncthreads();
    float inv = rsqrtf((red[0] + red[1] + red[2] + red[3]) * (1.0f / N_EMBD) + EPS);

    float4 gv = ((const float4*)g)[tid];
    float4 bv = ((const float4*)b)[tid];
    ushort4 o;
    o.x = f2bf(dx * inv * gv.x + bv.x);
    o.y = f2bf(dy * inv * gv.y + bv.y);
    o.z = f2bf(dz * inv * gv.z + bv.z);
    o.w = f2bf(dw * inv * gv.w + bv.w);
    ((ushort4*)(y + (size_t)row * N_EMBD))[tid] = o;
}

// ---------------------------------------------------------------------------
// fp32 -> bf16 elementwise (x -> x_bf), float4 granularity
// ---------------------------------------------------------------------------
__global__ __launch_bounds__(256) void f2bf_kernel(const float* __restrict__ x,
                                                   u16* __restrict__ y) {
    int i = blockIdx.x * 256 + threadIdx.x;
    float4 v = ((const float4*)x)[i];
    ushort4 o;
    o.x = f2bf(v.x); o.y = f2bf(v.y); o.z = f2bf(v.z); o.w = f2bf(v.w);
    ((ushort4*)y)[i] = o;
}

// ---------------------------------------------------------------------------
// bf16 MFMA GEMM, m97 structure: 128x128 tile, BK=32, 256 thr = 4 waves,
// A [M][K] bf16 row-major, B [N][K] bf16 (pre-transposed), fp32 accum.
// EPI: 0 = Cf = acc+bias ; 1 = Cf += acc+bias (residual) ; 2 = Cb = bf16(relu(acc+bias))
// ---------------------------------------------------------------------------
template <int EPI>
__global__ __launch_bounds__(256) void gemm_bf16_kernel(
    const u16* __restrict__ A, const u16* __restrict__ B,
    const float* __restrict__ bias, float* __restrict__ Cf,
    u16* __restrict__ Cb, int N, int K) {
    __shared__ u16 As[128 * 32];
    __shared__ u16 Bs[128 * 32];
    const int tid = threadIdx.x;
    const int w = tid >> 6, l = tid & 63;
    const int wr = w >> 1, wc = w & 1;
    const int m0 = blockIdx.y * 128, n0 = blockIdx.x * 128;

    const u16* gA = A + (size_t)(m0 + (tid >> 2)) * K + (tid & 3) * 8;
    const u16* gB = B + (size_t)(n0 + (tid >> 2)) * K + (tid & 3) * 8;
    u16* lA0 = &As[w * 512];
    u16* lA1 = &As[2048 + w * 512];
    u16* lB0 = &Bs[w * 512];
    u16* lB1 = &Bs[2048 + w * 512];
    const int fr = l & 15, fk = (l >> 4) * 8;

    f32x4 acc[4][4];
    #pragma unroll
    for (int i = 0; i < 4; ++i)
        #pragma unroll
        for (int j = 0; j < 4; ++j) acc[i][j] = (f32x4){0.f, 0.f, 0.f, 0.f};

    for (int k0 = 0; k0 < K; k0 += 32) {
        glds16(gA + k0, lA0);
        glds16(gA + k0 + (size_t)64 * K, lA1);
        glds16(gB + k0, lB0);
        glds16(gB + k0 + (size_t)64 * K, lB1);
        __syncthreads();
        bf16x8 af[4], bfr[4];
        #pragma unroll
        for (int i = 0; i < 4; ++i)
            af[i] = *(const bf16x8*)&As[(wr * 64 + i * 16 + fr) * 32 + fk];
        #pragma unroll
        for (int j = 0; j < 4; ++j)
            bfr[j] = *(const bf16x8*)&Bs[(wc * 64 + j * 16 + fr) * 32 + fk];
        #pragma unroll
        for (int i = 0; i < 4; ++i)
            #pragma unroll
            for (int j = 0; j < 4; ++j)
                acc[i][j] = __builtin_amdgcn_mfma_f32_16x16x32_bf16(af[i], bfr[j], acc[i][j], 0, 0, 0);
        __syncthreads();
    }

    const int rb = m0 + wr * 64 + (l >> 4) * 4;
    const int cb = n0 + wc * 64 + (l & 15);
    #pragma unroll
    for (int j = 0; j < 4; ++j) {
        const int col = cb + j * 16;
        const float bz = bias[col];
        #pragma unroll
        for (int i = 0; i < 4; ++i) {
            #pragma unroll
            for (int r = 0; r < 4; ++r) {
                const size_t idx = (size_t)(rb + i * 16 + r) * N + col;
                float v = acc[i][j][r] + bz;
                if (EPI == 0) Cf[idx] = v;
                else if (EPI == 1) Cf[idx] += v;
                else Cb[idx] = f2bf(fmaxf(v, 0.f));
            }
        }
    }
}

// ---------------------------------------------------------------------------
// QKV GEMM (same core), fused RoPE epilogue, scatter to [B,H,T,D] fp32.
// grid (8, 16, 3): z = sel (q,k,v). N=K=1024.
// ---------------------------------------------------------------------------
__global__ __launch_bounds__(256) void qkv_gemm_kernel(
    const u16* __restrict__ A, const u16* __restrict__ Bq,
    const u16* __restrict__ Bk, const u16* __restrict__ Bv,
    float* __restrict__ q, float* __restrict__ k, float* __restrict__ v,
    const float* __restrict__ cosT, const float* __restrict__ sinT) {
    const int sel = blockIdx.z;
    const u16* B = (sel == 0) ? Bq : (sel == 1) ? Bk : Bv;
    float* D = (sel == 0) ? q : (sel == 1) ? k : v;
    const int K = N_EMBD;

    __shared__ u16 As[128 * 32];
    __shared__ u16 Bs[128 * 32];
    const int tid = threadIdx.x;
    const int w = tid >> 6, l = tid & 63;
    const int wr = w >> 1, wc = w & 1;
    const int m0 = blockIdx.y * 128, n0 = blockIdx.x * 128;

    const u16* gA = A + (size_t)(m0 + (tid >> 2)) * K + (tid & 3) * 8;
    const u16* gB = B + (size_t)(n0 + (tid >> 2)) * K + (tid & 3) * 8;
    u16* lA0 = &As[w * 512];
    u16* lA1 = &As[2048 + w * 512];
    u16* lB0 = &Bs[w * 512];
    u16* lB1 = &Bs[2048 + w * 512];
    const int fr = l & 15, fk = (l >> 4) * 8;

    f32x4 acc[4][4];
    #pragma unroll
    for (int i = 0; i < 4; ++i)
        #pragma unroll
        for (int j = 0; j < 4; ++j) acc[i][j] = (f32x4){0.f, 0.f, 0.f, 0.f};

    for (int k0 = 0; k0 < K; k0 += 32) {
        glds16(gA + k0, lA0);
        glds16(gA + k0 + (size_t)64 * K, lA1);
        glds16(gB + k0, lB0);
        glds16(gB + k0 + (size_t)64 * K, lB1);
        __syncthreads();
        bf16x8 af[4], bfr[4];
        #pragma unroll
        for (int i = 0; i < 4; ++i)
            af[i] = *(const bf16x8*)&As[(wr * 64 + i * 16 + fr) * 32 + fk];
        #pragma unroll
        for (int j = 0; j < 4; ++j)
            bfr[j] = *(const bf16x8*)&Bs[(wc * 64 + j * 16 + fr) * 32 + fk];
        #pragma unroll
        for (int i = 0; i < 4; ++i)
            #pragma unroll
            for (int j = 0; j < 4; ++j)
                acc[i][j] = __builtin_amdgcn_mfma_f32_16x16x32_bf16(af[i], bfr[j], acc[i][j], 0, 0, 0);
        __syncthreads();
    }

    const int rb = m0 + wr * 64 + (l >> 4) * 4;
    const int cb = n0 + wc * 64 + (l & 15);
    #pragma unroll
    for (int j = 0; j < 4; ++j) {
        const int n = cb + j * 16;
        const int h = n >> 6, d = n & 63;
        #pragma unroll
        for (int i = 0; i < 4; ++i) {
            #pragma unroll
            for (int r = 0; r < 4; ++r) {
                const int row = rb + i * 16 + r;
                const int b = row >> 10, t = row & (TBLK - 1);
                float val = acc[i][j][r];
                float pv = __shfl_xor(val, 1);   // partner column (d^1)
                if (sel < 2) {
                    float c = cosT[t * 32 + (d >> 1)];
                    float s = sinT[t * 32 + (d >> 1)];
                    val = (d & 1) ? (pv * s + val * c) : (val * c - pv * s);
                }
                D[(((size_t)(b * N_HEADS + h)) * TBLK + t) * HEAD_DIM + d] = val;
            }
        }
    }
}

// ---------------------------------------------------------------------------
// Flash-tile attention, fp32. Block = 256 thr per (q-tile 64, h, b).
// 4x4 register blocking; online softmax; writes o as bf16 [B*T][H*D].
// ---------------------------------------------------------------------------
__global__ __launch_bounds__(256) void attn2_kernel(const float* __restrict__ q,
                                                    const float* __restrict__ k,
                                                    const float* __restrict__ v,
                                                    u16* __restrict__ obf) {
    const int qt = blockIdx.x, h = blockIdx.y, b = blockIdx.z;
    const int tid = threadIdx.x;
    __shared__ float qT[64][68];   // [d][row], pre-scaled
    __shared__ float kT[64][68];   // [d][s]
    __shared__ float vs[64][68];   // [s][d]
    __shared__ float pT[64][68];   // [s][row]

    const size_t bh = ((size_t)(b * N_HEADS + h)) * TBLK * HEAD_DIM;
    const int srow = tid >> 2, dbase = (tid & 3) * 16;

    {   // stage qT (transposed, scaled)
        const float* gq = q + bh + (size_t)(qt * 64 + srow) * HEAD_DIM + dbase;
        #pragma unroll
        for (int u = 0; u < 4; ++u) {
            float4 t4 = *(const float4*)(gq + u * 4);
            qT[dbase + u * 4 + 0][srow] = t4.x * SCALE;
            qT[dbase + u * 4 + 1][srow] = t4.y * SCALE;
            qT[dbase + u * 4 + 2][srow] = t4.z * SCALE;
            qT[dbase + u * 4 + 3][srow] = t4.w * SCALE;
        }
    }

    const int r0 = (tid >> 4) * 4;   // 4 q-rows
    const int c0 = (tid & 15) * 4;   // 4 cols (s in scores, d in PV)
    float m[4], lsum[4], o[4][4];
    #pragma unroll
    for (int i = 0; i < 4; ++i) {
        m[i] = -INFINITY; lsum[i] = 0.f;
        #pragma unroll
        for (int j = 0; j < 4; ++j) o[i][j] = 0.f;
    }

    for (int st = 0; st <= qt; ++st) {
        __syncthreads();
        const float* gk = k + bh + (size_t)(st * 64 + srow) * HEAD_DIM + dbase;
        const float* gv = v + bh + (size_t)(st * 64 + srow) * HEAD_DIM + dbase;
        #pragma unroll
        for (int u = 0; u < 4; ++u) {
            float4 kv = *(const float4*)(gk + u * 4);
            kT[dbase + u * 4 + 0][srow] = kv.x;
            kT[dbase + u * 4 + 1][srow] = kv.y;
            kT[dbase + u * 4 + 2][srow] = kv.z;
            kT[dbase + u * 4 + 3][srow] = kv.w;
            *(float4*)&vs[srow][dbase + u * 4] = *(const float4*)(gv + u * 4);
        }
        __syncthreads();

        float sc[4][4];
        #pragma unroll
        for (int i = 0; i < 4; ++i)
            #pragma unroll
            for (int j = 0; j < 4; ++j) sc[i][j] = 0.f;
        for (int d = 0; d < 64; ++d) {
            float4 qa = *(const float4*)&qT[d][r0];
            float4 kb = *(const float4*)&kT[d][c0];
            #pragma unroll
            for (int i = 0; i < 4; ++i)
                #pragma unroll
                for (int j = 0; j < 4; ++j)
                    sc[i][j] += (&qa.x)[i] * (&kb.x)[j];
        }
        if (st == qt) {
            #pragma unroll
            for (int i = 0; i < 4; ++i)
                #pragma unroll
                for (int j = 0; j < 4; ++j)
                    if (c0 + j > r0 + i) sc[i][j] = -INFINITY;
        }

        float rm[4], al[4], rs[4], p[4][4];
        #pragma unroll
        for (int i = 0; i < 4; ++i)
            rm[i] = fmaxf(fmaxf(sc[i][0], sc[i][1]), fmaxf(sc[i][2], sc[i][3]));
        #pragma unroll
        for (int off = 1; off < 16; off <<= 1)
            #pragma unroll
            for (int i = 0; i < 4; ++i) rm[i] = fmaxf(rm[i], __shfl_xor(rm[i], off));
        #pragma unroll
        for (int i = 0; i < 4; ++i) {
            float mn = fmaxf(m[i], rm[i]);
            al[i] = __expf(m[i] - mn);
            m[i] = mn;
        }
        #pragma unroll
        for (int i = 0; i < 4; ++i) {
            #pragma unroll
            for (int j = 0; j < 4; ++j) p[i][j] = __expf(sc[i][j] - m[i]);
            rs[i] = p[i][0] + p[i][1] + p[i][2] + p[i][3];
        }
        #pragma unroll
        for (int off = 1; off < 16; off <<= 1)
            #pragma unroll
            for (int i = 0; i < 4; ++i) rs[i] += __shfl_xor(rs[i], off);
        #pragma unroll
        for (int i = 0; i < 4; ++i) {
            lsum[i] = lsum[i] * al[i] + rs[i];
            #pragma unroll
            for (int j = 0; j < 4; ++j) o[i][j] *= al[i];
        }
        #pragma unroll
        for (int i = 0; i < 4; ++i)
            #pragma unroll
            for (int j = 0; j < 4; ++j) pT[c0 + j][r0 + i] = p[i][j];
        __syncthreads();
        for (int s = 0; s < 64; ++s) {
            float4 pa = *(const float4*)&pT[s][r0];
            float4 vb = *(const float4*)&vs[s][c0];
            #pragma unroll
            for (int i = 0; i < 4; ++i)
                #pragma unroll
                for (int j = 0; j < 4; ++j)
                    o[i][j] += (&pa.x)[i] * (&vb.x)[j];
        }
    }

    const int grow = b * TBLK + qt * 64;
    #pragma unroll
    for (int i = 0; i < 4; ++i) {
        float inv = 1.0f / lsum[i];
        ushort4 o4;
        o4.x = f2bf(o[i][0] * inv);
        o4.y = f2bf(o[i][1] * inv);
        o4.z = f2bf(o[i][2] * inv);
        o4.w = f2bf(o[i][3] * inv);
        *(ushort4*)&obf[(size_t)(grow + r0 + i) * N_EMBD + h * HEAD_DIM + c0] = o4;
    }
}

// ---------------------------------------------------------------------------
// NLL + loss reduce
// ---------------------------------------------------------------------------
__global__ __launch_bounds__(256) void nll_kernel(const float* __restrict__ logits,
                                                  const int* __restrict__ targets,
                                                  float* __restrict__ nll) {
    int row = blockIdx.x;
    int tid = threadIdx.x;
    const float* lr = logits + (size_t)row * VOCAB;
    __shared__ float red[4];

    float mx = -INFINITY;
    for (int c = tid; c < VOCAB; c += 256) mx = fmaxf(mx, lr[c]);
    #pragma unroll
    for (int off = 32; off; off >>= 1) mx = fmaxf(mx, __shfl_xor(mx, off));
    if ((tid & 63) == 0) red[tid >> 6] = mx;
    __syncthreads();
    mx = fmaxf(fmaxf(red[0], red[1]), fmaxf(red[2], red[3]));

    float se = 0.0f;
    for (int c = tid; c < VOCAB; c += 256) se += expf(lr[c] - mx);
    #pragma unroll
    for (int off = 32; off; off >>= 1) se += __shfl_xor(se, off);
    __syncthreads();
    if ((tid & 63) == 0) red[tid >> 6] = se;
    __syncthreads();
    se = red[0] + red[1] + red[2] + red[3];

    if (tid == 0) {
        float lt = lr[targets[row]];
        nll[row] = -(lt - mx - logf(se));
    }
}

__global__ __launch_bounds__(256) void loss_reduce_kernel(const float* __restrict__ nll,
                                                          float* __restrict__ out) {
    int tid = threadIdx.x;
    float s = 0.0f;
    for (int i = tid; i < ROWS; i += 256) s += nll[i];
    #pragma unroll
    for (int off = 32; off; off >>= 1) s += __shfl_xor(s, off);
    __shared__ float red[4];
    if ((tid & 63) == 0) red[tid >> 6] = s;
    __syncthreads();
    if (tid == 0) out[0] = (red[0] + red[1] + red[2] + red[3]) * (1.0f / ROWS);
}

// ---------------------------------------------------------------------------
extern "C" void kernel_launch(void* const* d_in, const int* in_sizes, int n_in,
                              void* d_out, int out_size, void* d_ws, size_t ws_size,
                              hipStream_t stream) {
    const int*   idx     = (const int*)d_in[0];
    const int*   targets = (const int*)d_in[1];
    const float* emb     = (const float*)d_in[2];
    const float* wq      = (const float*)d_in[3];
    const float* wk      = (const float*)d_in[4];
    const float* wv      = (const float*)d_in[5];
    const float* wproj   = (const float*)d_in[6];
    const float* bproj   = (const float*)d_in[7];
    const float* w1      = (const float*)d_in[8];
    const float* b1      = (const float*)d_in[9];
    const float* w2      = (const float*)d_in[10];
    const float* b2      = (const float*)d_in[11];
    const float* ln1g    = (const float*)d_in[12];
    const float* ln1b    = (const float*)d_in[13];
    const float* ln2g    = (const float*)d_in[14];
    const float* ln2b    = (const float*)d_in[15];
    const float* lmw     = (const float*)d_in[16];
    const float* lmb     = (const float*)d_in[17];

    float* out = (float*)d_out;
    u16*   ob  = (u16*)d_out;
    const size_t M1 = 1u << 20;

    // d_out scratch (dead before LM-head writes logits). float offsets:
    u16*   yb    = ob;                      // bf16 [2048][1024]   floats [0,1M)
    float* qf    = out + 1 * M1;            // fp32 [B,H,T,D]      [1M,3M)
    float* kf    = out + 3 * M1;            //                     [3M,5M)
    float* vf    = out + 5 * M1;            //                     [5M,7M)
    u16*   obf   = ob + 14 * M1;            // bf16 [2048][1024]   [7M,8M)
    u16*   act   = ob + 16 * M1;            // bf16 [2048][4096]   [8M,12M)
    u16*   wq_t  = ob + 24 * M1;            // 6 x [1024][1024]    [12M,15M)
    u16*   wk_t  = ob + 30 * M1;            //                     [15M,18M)
    u16*   wv_t  = ob + 36 * M1;            //                     [18M,21M)
    u16*   wp_t  = ob + 42 * M1;            //                     [21M,24M)
    u16*   w1_t  = ob + 48 * M1;            // 6 x [4096][1024]    [24M,36M)
    u16*   w2_t  = ob + 72 * M1;            // 6 x [1024][4096]    [36M,48M)

    // d_ws: survives until after logits are written. (needs ~79 MB)
    float* x     = (float*)d_ws;            // fp32 [2048][1024]
    u16*   xbf   = (u16*)d_ws + 4 * M1;     // bf16 [2048][1024]   floats [2M,3M)
    float* cosT  = (float*)d_ws + 3 * M1;
    float* sinT  = cosT + 32768;
    float* nll   = sinT + 32768;
    u16*   lmw_t = (u16*)d_ws + 6553600;    // bf16 [32000][1024]  floats [3.125M, 19.6M)

    embed_kernel<<<ROWS, 256, 0, stream>>>(idx, emb, x);
    rope_table_kernel<<<128, 256, 0, stream>>>(cosT, sinT);

    // weight conversions (transpose + bf16)
    convT_kernel<<<dim3(1000, 32, 1), 256, 0, stream>>>(lmw, lmw_t, 1024, VOCAB, 0, 0);
    convT_kernel<<<dim3(2, 32, 96), 256, 0, stream>>>(wq, wq_t, 1024, 64, 65536, 65536);
    convT_kernel<<<dim3(2, 32, 96), 256, 0, stream>>>(wk, wk_t, 1024, 64, 65536, 65536);
    convT_kernel<<<dim3(2, 32, 96), 256, 0, stream>>>(wv, wv_t, 1024, 64, 65536, 65536);
    convT_kernel<<<dim3(32, 32, 6), 256, 0, stream>>>(wproj, wp_t, 1024, 1024, 1048576, 1048576);
    convT_kernel<<<dim3(128, 32, 6), 256, 0, stream>>>(w1, w1_t, 1024, 4096, 4194304, 4194304);
    convT_kernel<<<dim3(32, 128, 6), 256, 0, stream>>>(w2, w2_t, 4096, 1024, 4194304, 4194304);

    for (int l = 0; l < NLAYER; ++l) {
        const u16* wq_l = wq_t + (size_t)l * 1048576;
        const u16* wk_l = wk_t + (size_t)l * 1048576;
        const u16* wv_l = wv_t + (size_t)l * 1048576;
        const u16* wp_l = wp_t + (size_t)l * 1048576;
        const u16* w1_l = w1_t + (size_t)l * 4194304;
        const u16* w2_l = w2_t + (size_t)l * 4194304;

        ln_kernel<<<ROWS, 256, 0, stream>>>(x, ln1g + l * N_EMBD, ln1b + l * N_EMBD, yb);
        qkv_gemm_kernel<<<dim3(8, 16, 3), 256, 0, stream>>>(
            yb, wq_l, wk_l, wv_l, qf, kf, vf, cosT, sinT);
        attn2_kernel<<<dim3(16, N_HEADS, BATCH), 256, 0, stream>>>(qf, kf, vf, obf);
        gemm_bf16_kernel<1><<<dim3(8, 16), 256, 0, stream>>>(
            obf, wp_l, bproj + l * N_EMBD, x, nullptr, N_EMBD, N_EMBD);
        ln_kernel<<<ROWS, 256, 0, stream>>>(x, ln2g + l * N_EMBD, ln2b + l * N_EMBD, yb);
        gemm_bf16_kernel<2><<<dim3(32, 16), 256, 0, stream>>>(
            yb, w1_l, b1 + (size_t)l * 4 * N_EMBD, nullptr, act, 4 * N_EMBD, N_EMBD);
        gemm_bf16_kernel<1><<<dim3(8, 16), 256, 0, stream>>>(
            act, w2_l, b2 + l * N_EMBD, x, nullptr, N_EMBD, 4 * N_EMBD);
    }

    f2bf_kernel<<<2048, 256, 0, stream>>>(x, xbf);
    gemm_bf16_kernel<0><<<dim3(250, 16), 256, 0, stream>>>(
        xbf, lmw_t, lmb, out, nullptr, VOCAB, N_EMBD);
    nll_kernel<<<ROWS, 256, 0, stream>>>(out, targets, nll);
    loss_reduce_kernel<<<1, 256, 0, stream>>>(nll, out + (size_t)ROWS * VOCAB);
}